// Round 9
// baseline (865.684 us; speedup 1.0000x reference)
//
#include <hip/hip_runtime.h>

#define N_NODES 50000
#define N_EDGES 800000
#define IN_DIM  256
#define OUT_DIM 64
#define NBKT    784               // ceil(50000/64) buckets of 64 dst nodes

// --- d_ws byte layout (16B-aligned) ----------------------------------------
#define WS_SUPPORT 0              // 12,800,000 B
#define WS_COUNTS  12800000       // 784 ints (padded)
#define WS_OFFSETS 12803200       // 785 ints (padded)
#define WS_CURSOR  12806400       // 784 ints (padded)
#define WS_RECS    12809600       // 800000 * 8 B = 6.4 MB
// total ~19.2 MB

// ---------------------------------------------------------------------------
// Kernel 1: support = input @ W.  64 rows/block, 512 threads (8 waves x 8
// cols) -> 782 blocks x 8 waves = 24 waves/CU ceiling (75%). lane = row.
// X staged rotated (slot=(k+row)&63 -> 2-way bank alias = free, m136) via
// coalesced float4. W chunk staged in LDS too: inner loop reads W via
// wave-uniform ds_read_b128 (broadcast, conflict-free) -> NO s_load in the
// loop, so no SMEM/DS lgkmcnt mixing. Per k: 1 ds_read_b32 + 2 bcast b128 +
// 8 FMA -> VALU-bound. Floor ~10.4 us.
// ---------------------------------------------------------------------------
__global__ __launch_bounds__(512) void gcn_gemm(const float* __restrict__ input,
                                                const float* __restrict__ W,
                                                float* __restrict__ support)
{
    __shared__ float Xs[64][64];   // 16 KiB
    __shared__ float Ws[64][64];   // 16 KiB (one 64-k chunk of W)
    const int tid  = threadIdx.x;
    const int lane = tid & 63;
    const int c0   = (tid >> 6) * 8;          // wave's first output col
    const int r0   = blockIdx.x * 64;

    float acc[8] = {0.f,0.f,0.f,0.f,0.f,0.f,0.f,0.f};

    for (int kc = 0; kc < 4; ++kc) {
        // stage X rows r0..r0+63, k = kc*64..+63 (coalesced float4, rotated)
        #pragma unroll
        for (int it = 0; it < 2; ++it) {
            const int F  = it * 512 + tid;    // flat float4 idx 0..1023
            const int r  = F >> 4;            // 0..63
            const int k4 = (F & 15) * 4;      // 0..60
            int rr = r0 + r; if (rr > N_NODES - 1) rr = N_NODES - 1;
            const float4 xv = *(const float4*)(input + (size_t)rr * IN_DIM + kc * 64 + k4);
            Xs[r][(k4 + 0 + r) & 63] = xv.x;
            Xs[r][(k4 + 1 + r) & 63] = xv.y;
            Xs[r][(k4 + 2 + r) & 63] = xv.z;
            Xs[r][(k4 + 3 + r) & 63] = xv.w;
        }
        // stage W chunk: W[kc*64+k][n] is already k-major -> direct copy
        {
            const float4* Wg = (const float4*)(W + (size_t)kc * 64 * OUT_DIM);
            float4*       Wl = (float4*)&Ws[0][0];
            Wl[tid]       = Wg[tid];
            Wl[tid + 512] = Wg[tid + 512];
        }
        __syncthreads();
        #pragma unroll 8
        for (int k6 = 0; k6 < 64; ++k6) {
            const float  x  = Xs[lane][(k6 + lane) & 63];
            const float4 w0 = *(const float4*)&Ws[k6][c0];      // bcast b128
            const float4 w1 = *(const float4*)&Ws[k6][c0 + 4];  // bcast b128
            acc[0] += x * w0.x; acc[1] += x * w0.y;
            acc[2] += x * w0.z; acc[3] += x * w0.w;
            acc[4] += x * w1.x; acc[5] += x * w1.y;
            acc[6] += x * w1.z; acc[7] += x * w1.w;
        }
        __syncthreads();
    }

    const int row = r0 + lane;
    if (row < N_NODES) {
        float* op = support + (size_t)row * OUT_DIM + c0;
        *(float4*)(op)     = make_float4(acc[0], acc[1], acc[2], acc[3]);
        *(float4*)(op + 4) = make_float4(acc[4], acc[5], acc[6], acc[7]);
    }
}

// ---------------------------------------------------------------------------
// Kernel 2: coarse histogram: counts[dst>>6]++  (784 counters, pre-zeroed)
// ---------------------------------------------------------------------------
__global__ __launch_bounds__(256) void gcn_hist(const int* __restrict__ dst,
                                                int* __restrict__ counts)
{
    const int e = blockIdx.x * 256 + threadIdx.x;
    if (e < N_EDGES) atomicAdd(&counts[dst[e] >> 6], 1);
}

// ---------------------------------------------------------------------------
// Kernel 3: exclusive scan of 784 counts -> offsets[785], cursor copy.
// Single block, 256 threads, 4 chunks.
// ---------------------------------------------------------------------------
__global__ __launch_bounds__(256) void gcn_scan(const int* __restrict__ counts,
                                                int* __restrict__ offsets,
                                                int* __restrict__ cursor)
{
    __shared__ int wsum[4];
    const int tid = threadIdx.x, lane = tid & 63, wid = tid >> 6;
    int running = 0;
    for (int c = 0; c < 4; ++c) {            // 4*256 = 1024 >= 785
        const int i    = c * 256 + tid;
        const int orig = (i < NBKT) ? counts[i] : 0;
        int v = orig;
        #pragma unroll
        for (int d = 1; d < 64; d <<= 1) {
            const int u = __shfl_up(v, d);
            if (lane >= d) v += u;
        }
        if (lane == 63) wsum[wid] = v;
        __syncthreads();
        int pre = running;
        for (int ww = 0; ww < wid; ++ww) pre += wsum[ww];
        const int excl = pre + v - orig;
        if (i <= NBKT) {
            offsets[i] = excl;
            if (i < NBKT) cursor[i] = excl;
        }
        running += wsum[0] + wsum[1] + wsum[2] + wsum[3];
        __syncthreads();                     // protect wsum reuse
    }
}

// ---------------------------------------------------------------------------
// Kernel 4: scatter edges into coarse buckets. Appends to 784 sequential
// streams -> only ~784 open 64B lines (L2-resident) -> EA writes ~6.4 MB
// instead of 52 MB (8x less). rec.x = src (16b) | (dst&63)<<16 ; rec.y = val.
// ---------------------------------------------------------------------------
__global__ __launch_bounds__(256) void gcn_build(const int*   __restrict__ src,
                                                 const int*   __restrict__ dst,
                                                 const float* __restrict__ val,
                                                 int*  __restrict__ cursor,
                                                 int2* __restrict__ recs)
{
    const int e = blockIdx.x * 256 + threadIdx.x;
    if (e < N_EDGES) {
        const int d   = dst[e];
        const int pos = atomicAdd(&cursor[d >> 6], 1);
        recs[pos] = make_int2(src[e] | ((d & 63) << 16), __float_as_int(val[e]));
    }
}

// ---------------------------------------------------------------------------
// Kernel 5: per-bucket accumulate. One block per bucket (64 dst nodes),
// 512 threads (8 waves). Zeroed 64x64 f32 LDS tile; each wave streams its
// stride-8 slice of the bucket's records with a 4-deep named-register
// prefetch (rule #20), ds_add_f32 into tile[dst&63][lane] (bank 2-way =
// free). Epilogue: out = tile + bias, written once, coalesced. No global
// atomics anywhere.
// ---------------------------------------------------------------------------
__global__ __launch_bounds__(512) void gcn_spmm(const float* __restrict__ support,
                                                const int2*  __restrict__ recs,
                                                const int*   __restrict__ offsets,
                                                const float* __restrict__ bias,
                                                float* __restrict__ out)
{
    __shared__ float tile[64][64];   // 16 KiB
    const int tid = threadIdx.x, lane = tid & 63, wid = tid >> 6;
    const int b = blockIdx.x;

    {   // zero tile
        float4* t4 = (float4*)&tile[0][0];
        t4[tid]       = make_float4(0.f, 0.f, 0.f, 0.f);
        t4[tid + 512] = make_float4(0.f, 0.f, 0.f, 0.f);
    }
    __syncthreads();

    const int beg = offsets[b];
    const int end = offsets[b + 1];
    const int2* rp = recs + beg + wid;              // this wave's stride-8 slice
    const int nrec = (end - beg - wid + 7) >> 3;    // records for this wave (>=0 iff end-beg>wid)

    if (end - beg > wid) {
        int t = 0;
        if (nrec >= 4) {
            int2 ra = rp[0], rb = rp[8], rc = rp[16], rd = rp[24];
            float sa = support[(size_t)(ra.x & 0xFFFF) * OUT_DIM + lane];
            float sb = support[(size_t)(rb.x & 0xFFFF) * OUT_DIM + lane];
            float sc = support[(size_t)(rc.x & 0xFFFF) * OUT_DIM + lane];
            float sd = support[(size_t)(rd.x & 0xFFFF) * OUT_DIM + lane];
            for (; t + 8 <= nrec; t += 4) {
                const int2 na = rp[(t + 4) * 8], nb = rp[(t + 5) * 8];
                const int2 nc = rp[(t + 6) * 8], nd = rp[(t + 7) * 8];
                const float ta = support[(size_t)(na.x & 0xFFFF) * OUT_DIM + lane];
                const float tb = support[(size_t)(nb.x & 0xFFFF) * OUT_DIM + lane];
                const float tc = support[(size_t)(nc.x & 0xFFFF) * OUT_DIM + lane];
                const float td = support[(size_t)(nd.x & 0xFFFF) * OUT_DIM + lane];
                atomicAdd(&tile[(ra.x >> 16) & 63][lane], __int_as_float(ra.y) * sa);
                atomicAdd(&tile[(rb.x >> 16) & 63][lane], __int_as_float(rb.y) * sb);
                atomicAdd(&tile[(rc.x >> 16) & 63][lane], __int_as_float(rc.y) * sc);
                atomicAdd(&tile[(rd.x >> 16) & 63][lane], __int_as_float(rd.y) * sd);
                ra = na; sa = ta;  rb = nb; sb = tb;
                rc = nc; sc = tc;  rd = nd; sd = td;
            }
            atomicAdd(&tile[(ra.x >> 16) & 63][lane], __int_as_float(ra.y) * sa);
            atomicAdd(&tile[(rb.x >> 16) & 63][lane], __int_as_float(rb.y) * sb);
            atomicAdd(&tile[(rc.x >> 16) & 63][lane], __int_as_float(rc.y) * sc);
            atomicAdd(&tile[(rd.x >> 16) & 63][lane], __int_as_float(rd.y) * sd);
            t += 4;
        }
        for (; t < nrec; ++t) {
            const int2 r = rp[t * 8];
            const float s = support[(size_t)(r.x & 0xFFFF) * OUT_DIM + lane];
            atomicAdd(&tile[(r.x >> 16) & 63][lane], __int_as_float(r.y) * s);
        }
    }
    __syncthreads();

    // epilogue: wave wid writes rows wid*8 .. wid*8+7, coalesced 256B rows
    const float bj = bias[lane];
    #pragma unroll
    for (int rr = 0; rr < 8; ++rr) {
        const int n = b * 64 + wid * 8 + rr;
        if (n < N_NODES)
            out[(size_t)n * OUT_DIM + lane] = tile[wid * 8 + rr][lane] + bj;
    }
}

// ---------------------------------------------------------------------------
extern "C" void kernel_launch(void* const* d_in, const int* in_sizes, int n_in,
                              void* d_out, int out_size, void* d_ws, size_t ws_size,
                              hipStream_t stream)
{
    const float* input  = (const float*)d_in[0];
    const float* weight = (const float*)d_in[1];
    const float* bias   = (const float*)d_in[2];
    const float* eval_  = (const float*)d_in[3];
    const int*   esrc   = (const int*)d_in[4];
    const int*   edst   = (const int*)d_in[5];
    float*       out    = (float*)d_out;

    char* ws = (char*)d_ws;
    float* support = (float*)(ws + WS_SUPPORT);
    int*   counts  = (int*)(ws + WS_COUNTS);
    int*   offsets = (int*)(ws + WS_OFFSETS);
    int*   cursor  = (int*)(ws + WS_CURSOR);
    int2*  recs    = (int2*)(ws + WS_RECS);

    hipMemsetAsync(counts, 0, NBKT * sizeof(int), stream);

    // support = X @ W
    gcn_gemm<<<(N_NODES + 63) / 64, 512, 0, stream>>>(input, weight, support);

    // coarse-bucket CSR build (784 buckets of 64 dst nodes)
    gcn_hist <<<(N_EDGES + 255) / 256, 256, 0, stream>>>(edst, counts);
    gcn_scan <<<1, 256, 0, stream>>>(counts, offsets, cursor);
    gcn_build<<<(N_EDGES + 255) / 256, 256, 0, stream>>>(esrc, edst, eval_, cursor, recs);

    // per-bucket gather-accumulate + bias, single coalesced out-write
    gcn_spmm<<<NBKT, 512, 0, stream>>>(support, recs, offsets, bias, out);
}

// Round 11
// 250.144 us; speedup vs baseline: 3.4607x; 3.4607x over previous
//
#include <hip/hip_runtime.h>

#define N_NODES 50000
#define N_EDGES 800000
#define IN_DIM  256
#define OUT_DIM 64
#define NB      196               // ceil(N_NODES/256)

// --- d_ws byte layout (16B-aligned) ----------------------------------------
#define WS_SUPPORT 0              // 12,800,000 B
#define WS_COUNTS  12800000
#define WS_OFFSETS 13000064
#define WS_CURSOR  13200128
#define WS_BSUM    13400128
#define WS_BOFF    13400960
#define WS_RECS    13401792       // 800000 * 8 B
// total ~19.8 MB

// ---------------------------------------------------------------------------
// Kernel 1: support = input @ W.  Same proven tile as R8 (64 rows, lane=row,
// rotated X in LDS, W on the wave-uniform scalar path) but 512 threads =
// 8 waves x 8 cols -> 782 blocks x 8 waves = 24.4 waves/CU (76% occupancy
// ceiling vs R8's 12 waves/29.7%): doubles s_load latency hiding, the
// measured R8 bottleneck. Per k6: 1 conflict-free ds_read_b32 (rotation
// (k6+lane)&63 -> 2-way alias = free, m136) + s_load_dwordx8 + 8 FMA.
// ---------------------------------------------------------------------------
__global__ __launch_bounds__(512) void gcn_gemm(const float* __restrict__ input,
                                                const float* __restrict__ W,
                                                float* __restrict__ support)
{
    __shared__ float Xs[64][64];   // 16 KiB
    const int tid  = threadIdx.x;
    const int lane = tid & 63;
    const int w    = __builtin_amdgcn_readfirstlane(tid >> 6);  // 0..7
    const int c0   = w * 8;        // wave-uniform first output col
    const int r0   = blockIdx.x * 64;

    float acc[8] = {0.f,0.f,0.f,0.f,0.f,0.f,0.f,0.f};
    const float* Wb = W + c0;

    for (int kc = 0; kc < 4; ++kc) {
        // stage X rows r0..r0+63, k = kc*64..+63 (coalesced float4, rotated)
        #pragma unroll
        for (int it = 0; it < 2; ++it) {
            const int F  = it * 512 + tid;    // flat float4 idx 0..1023
            const int r  = F >> 4;            // 0..63
            const int k4 = (F & 15) * 4;      // 0..60
            int rr = r0 + r; if (rr > N_NODES - 1) rr = N_NODES - 1;
            const float4 xv = *(const float4*)(input + (size_t)rr * IN_DIM + kc * 64 + k4);
            Xs[r][(k4 + 0 + r) & 63] = xv.x;
            Xs[r][(k4 + 1 + r) & 63] = xv.y;
            Xs[r][(k4 + 2 + r) & 63] = xv.z;
            Xs[r][(k4 + 3 + r) & 63] = xv.w;
        }
        __syncthreads();
        const float* Wk = Wb + (size_t)(kc * 64) * OUT_DIM;
        #pragma unroll 8
        for (int k6 = 0; k6 < 64; ++k6) {
            const float x = Xs[lane][(k6 + lane) & 63];
            const float* wrow = Wk + (size_t)k6 * OUT_DIM;  // uniform -> s_load
            #pragma unroll
            for (int j = 0; j < 8; ++j)
                acc[j] += x * wrow[j];
        }
        __syncthreads();
    }

    const int row = r0 + lane;
    if (row < N_NODES) {
        float* op = support + (size_t)row * OUT_DIM + c0;
        *(float4*)(op)     = make_float4(acc[0], acc[1], acc[2], acc[3]);
        *(float4*)(op + 4) = make_float4(acc[4], acc[5], acc[6], acc[7]);
    }
}

// ---------------------------------------------------------------------------
// Kernel 2: histogram of dst (counts pre-zeroed by hipMemsetAsync)
// ---------------------------------------------------------------------------
__global__ __launch_bounds__(256) void gcn_hist(const int* __restrict__ dst,
                                                int* __restrict__ counts)
{
    const int e = blockIdx.x * 256 + threadIdx.x;
    if (e < N_EDGES) atomicAdd(&counts[dst[e]], 1);
}

// ---------------------------------------------------------------------------
// Kernels 3a/3b/3c: hierarchical exclusive scan of counts -> offsets, cursor
// ---------------------------------------------------------------------------
__global__ __launch_bounds__(256) void gcn_scanA(const int* __restrict__ counts,
                                                 int* __restrict__ bsum)
{
    __shared__ int wsum[4];
    const int tid = threadIdx.x, lane = tid & 63, wid = tid >> 6;
    const int i = blockIdx.x * 256 + tid;
    int v = (i < N_NODES) ? counts[i] : 0;
    #pragma unroll
    for (int d = 32; d > 0; d >>= 1) v += __shfl_down(v, d);
    if (lane == 0) wsum[wid] = v;
    __syncthreads();
    if (tid == 0) bsum[blockIdx.x] = wsum[0] + wsum[1] + wsum[2] + wsum[3];
}

__global__ __launch_bounds__(256) void gcn_scanB(const int* __restrict__ bsum,
                                                 int* __restrict__ boff)
{
    __shared__ int wsum[4];
    const int tid = threadIdx.x, lane = tid & 63, wid = tid >> 6;
    const int orig = (tid < NB) ? bsum[tid] : 0;
    int v = orig;
    #pragma unroll
    for (int d = 1; d < 64; d <<= 1) {
        const int u = __shfl_up(v, d);
        if (lane >= d) v += u;
    }
    if (lane == 63) wsum[wid] = v;
    __syncthreads();
    int pre = 0;
    for (int ww = 0; ww < wid; ++ww) pre += wsum[ww];
    if (tid < NB) boff[tid] = pre + v - orig;
}

__global__ __launch_bounds__(256) void gcn_scanC(const int* __restrict__ counts,
                                                 const int* __restrict__ boff,
                                                 int* __restrict__ offsets,
                                                 int* __restrict__ cursor)
{
    __shared__ int wsum[4];
    const int tid = threadIdx.x, lane = tid & 63, wid = tid >> 6;
    const int i = blockIdx.x * 256 + tid;
    const int orig = (i < N_NODES) ? counts[i] : 0;
    int v = orig;
    #pragma unroll
    for (int d = 1; d < 64; d <<= 1) {
        const int u = __shfl_up(v, d);
        if (lane >= d) v += u;
    }
    if (lane == 63) wsum[wid] = v;
    __syncthreads();
    int pre = boff[blockIdx.x];
    for (int ww = 0; ww < wid; ++ww) pre += wsum[ww];
    const int excl = pre + v - orig;
    if (i < N_NODES) { offsets[i] = excl; cursor[i] = excl; }
    if (i == N_NODES - 1) offsets[N_NODES] = excl + orig;
}

// ---------------------------------------------------------------------------
// Kernel 4: bucket edges by dst: recs[pos] = (src, bits(val))
// ---------------------------------------------------------------------------
__global__ __launch_bounds__(256) void gcn_build(const int*   __restrict__ src,
                                                 const int*   __restrict__ dst,
                                                 const float* __restrict__ val,
                                                 int*  __restrict__ cursor,
                                                 int2* __restrict__ recs)
{
    const int e = blockIdx.x * 256 + threadIdx.x;
    if (e < N_EDGES) {
        const int d   = dst[e];
        const int pos = atomicAdd(&cursor[d], 1);
        recs[pos] = make_int2(src[e], __float_as_int(val[e]));
    }
}

// ---------------------------------------------------------------------------
// Kernel 5: per-node gather-accumulate, bias fused, no atomics.
// 4-deep rotating prefetch with NAMED registers (rule #20): ~16 serial
// L2/L3 round-trips per node -> ~4. readfirstlane(n) -> offsets/recs on the
// scalar path.
// ---------------------------------------------------------------------------
__global__ __launch_bounds__(256) void gcn_gather(const float* __restrict__ support,
                                                  const int2*  __restrict__ recs,
                                                  const int*   __restrict__ offsets,
                                                  const float* __restrict__ bias,
                                                  float* __restrict__ out)
{
    const int lane = threadIdx.x & 63;
    const int n = __builtin_amdgcn_readfirstlane(
                      (int)((blockIdx.x * 256 + threadIdx.x) >> 6));
    if (n >= N_NODES) return;

    const float b   = bias[lane];
    const int   beg = offsets[n];
    const int   end = offsets[n + 1];
    float acc = 0.f;
    int i = beg;

    if (end - beg >= 8) {
        int2 ra = recs[i],   rb = recs[i+1], rc = recs[i+2], rd = recs[i+3];
        float sa = support[(size_t)ra.x * OUT_DIM + lane];
        float sb = support[(size_t)rb.x * OUT_DIM + lane];
        float sc = support[(size_t)rc.x * OUT_DIM + lane];
        float sd = support[(size_t)rd.x * OUT_DIM + lane];
        for (; i + 8 <= end; i += 4) {
            const int2 na = recs[i+4], nb = recs[i+5], nc = recs[i+6], nd = recs[i+7];
            const float ta = support[(size_t)na.x * OUT_DIM + lane];
            const float tb = support[(size_t)nb.x * OUT_DIM + lane];
            const float tc = support[(size_t)nc.x * OUT_DIM + lane];
            const float td = support[(size_t)nd.x * OUT_DIM + lane];
            acc += __int_as_float(ra.y) * sa;
            acc += __int_as_float(rb.y) * sb;
            acc += __int_as_float(rc.y) * sc;
            acc += __int_as_float(rd.y) * sd;
            ra = na; sa = ta;  rb = nb; sb = tb;
            rc = nc; sc = tc;  rd = nd; sd = td;
        }
        acc += __int_as_float(ra.y) * sa + __int_as_float(rb.y) * sb
             + __int_as_float(rc.y) * sc + __int_as_float(rd.y) * sd;
        i += 4;
    }
    for (; i < end; ++i) {
        const int2 r = recs[i];
        acc += __int_as_float(r.y) * support[(size_t)r.x * OUT_DIM + lane];
    }
    out[(size_t)n * OUT_DIM + lane] = acc + b;
}

// ---------------------------------------------------------------------------
extern "C" void kernel_launch(void* const* d_in, const int* in_sizes, int n_in,
                              void* d_out, int out_size, void* d_ws, size_t ws_size,
                              hipStream_t stream)
{
    const float* input  = (const float*)d_in[0];
    const float* weight = (const float*)d_in[1];
    const float* bias   = (const float*)d_in[2];
    const float* eval_  = (const float*)d_in[3];
    const int*   esrc   = (const int*)d_in[4];
    const int*   edst   = (const int*)d_in[5];
    float*       out    = (float*)d_out;

    char* ws = (char*)d_ws;
    float* support = (float*)(ws + WS_SUPPORT);
    int*   counts  = (int*)(ws + WS_COUNTS);
    int*   offsets = (int*)(ws + WS_OFFSETS);
    int*   cursor  = (int*)(ws + WS_CURSOR);
    int*   bsum    = (int*)(ws + WS_BSUM);
    int*   boff    = (int*)(ws + WS_BOFF);
    int2*  recs    = (int2*)(ws + WS_RECS);

    hipMemsetAsync(counts, 0, N_NODES * sizeof(int), stream);

    // support = X @ W
    gcn_gemm<<<(N_NODES + 63) / 64, 512, 0, stream>>>(input, weight, support);

    // fine CSR-by-dst build (proven R8 path)
    gcn_hist <<<(N_EDGES + 255) / 256, 256, 0, stream>>>(edst, counts);
    gcn_scanA<<<NB, 256, 0, stream>>>(counts, bsum);
    gcn_scanB<<<1, 256, 0, stream>>>(bsum, boff);
    gcn_scanC<<<NB, 256, 0, stream>>>(counts, boff, offsets, cursor);
    gcn_build<<<(N_EDGES + 255) / 256, 256, 0, stream>>>(esrc, edst, eval_, cursor, recs);

    // out[n] = sum_{e: dst=n} val_e * support[src_e] + bias
    gcn_gather<<<(N_NODES * 64) / 256, 256, 0, stream>>>(support, recs, offsets, bias, out);
}